// Round 4
// baseline (273.529 us; speedup 1.0000x reference)
//
#include <hip/hip_runtime.h>
#include <math.h>

#define NN 8
#define HH 100
#define WW 152
#define HW (HH*WW)           // 15200
#define TT 256
#define TOPN 1000
#define POSTN 100
#define NMS_T 0.6f
#define IMGW 1216
#define IMGH 800
#define DWH_CLIP 4.135166556742356f   // log(1000/16)

typedef unsigned long long u64;
typedef unsigned int u32;

// ---------------- Kernel A: sigmoid-mean scores + centerness + threshold ----
__global__ __launch_bounds__(256) void score_kernel(
    const float* __restrict__ logits,      // [N, HW, T]
    const float* __restrict__ centerness,  // [N, HW]
    float* __restrict__ masked)            // [N*HW]
{
    int wid  = blockIdx.x * 4 + (threadIdx.x >> 6);
    int lane = threadIdx.x & 63;
    const float4 v = *(reinterpret_cast<const float4*>(logits + (size_t)wid * TT) + lane);
    float s = 0.f;
    s += __fdividef(1.f, 1.f + expf(-v.x));
    s += __fdividef(1.f, 1.f + expf(-v.y));
    s += __fdividef(1.f, 1.f + expf(-v.z));
    s += __fdividef(1.f, 1.f + expf(-v.w));
    #pragma unroll
    for (int off = 32; off; off >>= 1) s += __shfl_xor(s, off, 64);
    if (lane == 0) {
        float score = s * (1.0f / 256.0f);
        float c = centerness[wid];
        float ctr = 1.f / (1.f + expf(-c));
        masked[wid] = (score > 0.05f) ? score * ctr : 0.f;
    }
}

// ---------------- Kernel B: fused top-k + decode + mask-NMS, 1 block/image --
__global__ __launch_bounds__(256) void select_nms_kernel(
    const float* __restrict__ masked,   // [N*HW]
    const float* __restrict__ box_reg,  // [N,4,H,W]
    float* __restrict__ out)            // [N*POSTN*4] boxes ++ [N*POSTN] scores
{
    const int n   = blockIdx.x;
    const int tid = threadIdx.x;
    const int wv  = tid >> 6;
    const int PER = (HW + 255) / 256;   // 60

    u32 bits[PER];
    const float* mb = masked + (size_t)n * HW;
    #pragma unroll
    for (int j = 0; j < PER; j++) {
        int e = tid + j * 256;
        bits[j] = (e < HW) ? __float_as_uint(mb[e]) : 0u;   // all values >= 0
    }

    __shared__ int    parts[2][4];
    __shared__ u64    keys[256];
    __shared__ float4 sbox[256];
    __shared__ float  sscr[256];
    __shared__ float  sarea[256];
    __shared__ u64    smask[256 * 4];    // suppression rows, 8 KB
    __shared__ unsigned char ssupp[256]; // pre-suppressed by earlier-batch keeps
    __shared__ float4 kbox[POSTN + 4];   // kept boxes (cross-batch suppression)
    __shared__ int    keep_list[POSTN + 4];
    __shared__ int    s_cnt1, s_cnt2, s_nvalid, s_newkept;

    float* outb = out + (size_t)n * POSTN * 4;
    float* outs = out + (size_t)NN * POSTN * 4 + (size_t)n * POSTN;

    int  kept_total = 0;
    bool done = false;
    u32  thrPrev = 0xFFFFFFFFu;
    int  p = 0;

    for (int b = 0; b < 4 && !done; ++b) {
        const int limit = (b == 3) ? (TOPN - 3 * 256) : 256;   // rank cap 1000

        // ---- binary search: smallest thr with count(bits > thr) <= 256(b+1)-1
        const int target = 256 * (b + 1) - 1;
        u32 lo = 0u;
        u32 hi = (thrPrev < 0x3F800000u) ? thrPrev : 0x3F800000u;  // masked < 1.0
        while (lo < hi) {
            u32 mid = lo + ((hi - lo) >> 1);
            int c = 0;
            #pragma unroll
            for (int j = 0; j < PER; j++) c += (bits[j] > mid) ? 1 : 0;
            #pragma unroll
            for (int off = 32; off; off >>= 1) c += __shfl_xor(c, off, 64);
            if ((tid & 63) == 0) parts[p][wv] = c;
            __syncthreads();
            int tot = parts[p][0] + parts[p][1] + parts[p][2] + parts[p][3];
            p ^= 1;
            if (tot <= target) hi = mid; else lo = mid + 1;
        }
        const u32 thr = lo;

        // ---- compact this batch (strict window + tie fill)
        if (tid == 0) { s_cnt1 = 0; s_cnt2 = 0; s_nvalid = 0; s_newkept = 0; }
        keys[tid] = 0ull;
        ssupp[tid] = 0;
        __syncthreads();
        #pragma unroll
        for (int j = 0; j < PER; j++) {
            int e = tid + j * 256;
            u32 v = bits[j];
            if (e < HW && v > thr && v < thrPrev) {
                int pos = atomicAdd(&s_cnt1, 1);
                if (pos < 256) keys[pos] = (((u64)v) << 32) | (u32)(~e);
            }
        }
        __syncthreads();
        const int c1 = min(s_cnt1, 256);
        #pragma unroll
        for (int j = 0; j < PER; j++) {
            int e = tid + j * 256;
            if (e < HW && bits[j] == thr) {
                int q = atomicAdd(&s_cnt2, 1);
                if (c1 + q < 256) keys[c1 + q] = (((u64)thr) << 32) | (u32)(~e);
            }
        }
        __syncthreads();

        // ---- bitonic sort 256 u64 keys, descending
        for (int k = 2; k <= 256; k <<= 1) {
            for (int j2 = k >> 1; j2 > 0; j2 >>= 1) {
                int ixj = tid ^ j2;
                if (ixj > tid) {
                    u64 a = keys[tid], bb = keys[ixj];
                    bool sw = ((tid & k) == 0) ? (a < bb) : (a > bb);
                    if (sw) { keys[tid] = bb; keys[ixj] = a; }
                }
                __syncthreads();
            }
        }

        // ---- decode candidate at sorted position tid
        float4 myb = make_float4(0.f, 0.f, 0.f, 0.f);
        float   myscr = 0.f;
        {
            u64 kk = keys[tid];
            float s = __uint_as_float((u32)(kk >> 32));
            if (s > 0.f) {
                int loc = (int)(~(u32)kk);
                float acx = (float)(loc % WW) * 8.f + 4.f;   // analytic anchor,
                float acy = (float)(loc / WW) * 8.f + 4.f;   // bit-identical grid
                float a0 = acx - 32.f, a1 = acy - 32.f, a2 = acx + 32.f, a3 = acy + 32.f;
                float r0 = box_reg[((size_t)n * 4 + 0) * HW + loc];
                float r1 = box_reg[((size_t)n * 4 + 1) * HW + loc];
                float r2 = box_reg[((size_t)n * 4 + 2) * HW + loc];
                float r3 = box_reg[((size_t)n * 4 + 3) * HW + loc];
                float w  = a2 - a0 + 1.0f;
                float h  = a3 - a1 + 1.0f;
                float cx = a0 + 0.5f * w;
                float cy = a1 + 0.5f * h;
                float dx = r0 / 10.0f;
                float dy = r1 / 10.0f;
                float dw = fminf(r2 / 5.0f, DWH_CLIP);
                float dh = fminf(r3 / 5.0f, DWH_CLIP);
                float pcx = dx * w + cx;
                float pcy = dy * h + cy;
                float pw  = expf(dw) * w;
                float ph  = expf(dh) * h;
                float x1 = pcx - 0.5f * pw;
                float y1 = pcy - 0.5f * ph;
                float x2 = pcx + 0.5f * pw - 1.0f;
                float y2 = pcy + 0.5f * ph - 1.0f;
                myb.x = fminf(fmaxf(x1, 0.f), (float)(IMGW - 1));
                myb.y = fminf(fmaxf(y1, 0.f), (float)(IMGH - 1));
                myb.z = fminf(fmaxf(x2, 0.f), (float)(IMGW - 1));
                myb.w = fminf(fmaxf(y2, 0.f), (float)(IMGH - 1));
                myscr = sqrtf(s);
                if (tid < limit) atomicAdd(&s_nvalid, 1);
            }
            sbox[tid] = myb;
            sscr[tid] = myscr;
            sarea[tid] = (myb.z - myb.x + 1.f) * (myb.w - myb.y + 1.f);
        }
        __syncthreads();

        // ---- pre-suppression by keeps from earlier batches (rare path)
        if (kept_total > 0 && myscr > 0.f) {
            float marea = sarea[tid];
            for (int k = 0; k < kept_total; ++k) {
                float4 kb = kbox[k];
                float ix1 = fmaxf(myb.x, kb.x), iy1 = fmaxf(myb.y, kb.y);
                float ix2 = fminf(myb.z, kb.z), iy2 = fminf(myb.w, kb.w);
                float iw = fmaxf(ix2 - ix1 + 1.f, 0.f), ih = fmaxf(iy2 - iy1 + 1.f, 0.f);
                float inter = iw * ih;
                float karea = (kb.z - kb.x + 1.f) * (kb.w - kb.y + 1.f);
                float iou = inter / (marea + karea - inter);
                if (iou > NMS_T) { ssupp[tid] = 1; break; }
            }
        }

        // ---- pairwise suppression matrix: thread t builds row t (256 IoUs)
        {
            u64 m0 = 0, m1 = 0, m2 = 0, m3 = 0;
            if (myscr > 0.f) {
                float marea = sarea[tid];
                for (int j = 0; j < 256; ++j) {
                    float4 ob = sbox[j];                    // LDS broadcast read
                    float ix1 = fmaxf(myb.x, ob.x), iy1 = fmaxf(myb.y, ob.y);
                    float ix2 = fminf(myb.z, ob.z), iy2 = fminf(myb.w, ob.w);
                    float iw = fmaxf(ix2 - ix1 + 1.f, 0.f), ih = fmaxf(iy2 - iy1 + 1.f, 0.f);
                    float inter = iw * ih;
                    float iou = inter / (marea + sarea[j] - inter);
                    if (iou > NMS_T) {
                        u64 bit = 1ull << (j & 63);
                        switch (j >> 6) {
                            case 0: m0 |= bit; break;
                            case 1: m1 |= bit; break;
                            case 2: m2 |= bit; break;
                            default: m3 |= bit; break;
                        }
                    }
                }
            }
            smask[tid * 4 + 0] = m0;
            smask[tid * 4 + 1] = m1;
            smask[tid * 4 + 2] = m2;
            smask[tid * 4 + 3] = m3;
        }
        __syncthreads();

        // ---- wave-0 bitmask closure: loop runs once per KEEP (~100 iters)
        if (tid < 64) {
            const int l = tid;
            u32 alive = 0;
            #pragma unroll
            for (int k = 0; k < 4; k++) {
                int i = 4 * l + k;
                if (i < limit && sscr[i] > 0.f && ssupp[i] == 0) alive |= (1u << k);
            }
            int newkept = 0;
            while (kept_total + newkept < POSTN) {
                u64 bal = __ballot(alive != 0u);
                if (bal == 0ull) break;
                int w = __ffsll(bal) - 1;              // first lane with alive cand
                u32 aw = __shfl(alive, w, 64);
                int c = __ffs(aw) - 1;
                int i = 4 * w + c;                     // next greedy keep
                u64 row = smask[i * 4 + (l >> 4)];     // broadcast within 16 lanes
                u32 bits4 = (u32)((row >> ((4 * l) & 63)) & 0xFull);
                alive &= ~bits4;
                if (l == w) alive &= ~(1u << c);       // insurance self-clear
                if (l == 0) keep_list[newkept] = i;
                ++newkept;
            }
            if (tid == 0) s_newkept = newkept;
        }
        __syncthreads();

        // ---- write this batch's keeps, append to kept list
        const int nk = s_newkept;
        if (tid < nk) {
            int i = keep_list[tid];
            float4 kb = sbox[i];
            int pos = kept_total + tid;
            outb[pos * 4 + 0] = kb.x; outb[pos * 4 + 1] = kb.y;
            outb[pos * 4 + 2] = kb.z; outb[pos * 4 + 3] = kb.w;
            outs[pos] = sscr[i];
            kbox[pos] = kb;
        }
        __syncthreads();

        const int nvalid = s_nvalid;
        kept_total += nk;
        done = (kept_total >= POSTN) || (nvalid < limit);
        thrPrev = thr;
        __syncthreads();   // keys/ssupp reused next batch
    }

    // zero-fill remaining slots (d_out re-poisoned before every launch)
    for (int i = kept_total + tid; i < POSTN; i += 256) {
        outb[i * 4 + 0] = 0.f; outb[i * 4 + 1] = 0.f;
        outb[i * 4 + 2] = 0.f; outb[i * 4 + 3] = 0.f;
        outs[i] = 0.f;
    }
}

extern "C" void kernel_launch(void* const* d_in, const int* in_sizes, int n_in,
                              void* d_out, int out_size, void* d_ws, size_t ws_size,
                              hipStream_t stream) {
    const float* box_reg = (const float*)d_in[0];   // [N,4,H,W]
    const float* center  = (const float*)d_in[1];   // [N,1,H,W]
    // d_in[2] = anchors: computed analytically in-kernel (bit-identical grid)
    const float* logits  = (const float*)d_in[3];   // [N,HW,T]
    float* out = (float*)d_out;

    float* masked = (float*)d_ws;                   // N*HW floats

    score_kernel<<<(NN * HW) / 4, 256, 0, stream>>>(logits, center, masked);
    select_nms_kernel<<<NN, 256, 0, stream>>>(masked, box_reg, out);
}